// Round 6
// baseline (48.504 us; speedup 1.0000x reference)
//
#include <hip/hip_runtime.h>
#include <hip/hip_cooperative_groups.h>
#include <math.h>

namespace cg = cooperative_groups;

#define NB 256
#define NN 2048
#define NE 128
#define NORMC 0.08838834764831845f   // 1/sqrt(128)

// ---- T layout in d_ws (47 rows x 128 floats) ----
// 0-2  Qc_n  3 bQ1_n   4-5 Qc_d   6 bQ1_d      (wq1)
// 7-9  Qn_n 10 bQ2_n  11-12 Qn_d 13 bQ2_d      (wq2)
// 14-17 Qs  18 bQ3                             (wq3)
// 19-21 Kc_n 22 bKc_n 23-24 Kc_d 25 bKc_d      (wk1)
// 26-28 Ak  29 ck     30-31 Dk   32 dk         (wk2)
// 33-35 Vc_n 36 bVc_n 37-38 Vc_d 39 bVc_d      (wv1)
// 40-42 Av  43 cv     44-45 Dv   46 dv         (wv2)

__global__ __launch_bounds__(512)
void fused_kernel(const float* __restrict__ nodef, const float* __restrict__ state,
                  const float* __restrict__ Wn, const float* __restrict__ bn,
                  const float* __restrict__ Wd, const float* __restrict__ bd,
                  const float* __restrict__ Ws, const float* __restrict__ bs,
                  const float* __restrict__ wq, const float* __restrict__ wk,
                  const float* __restrict__ wv,
                  const int* __restrict__ curr_id, const int* __restrict__ next_id,
                  const void* __restrict__ maskp,
                  float* __restrict__ T, float* __restrict__ out)
{
  const int b = blockIdx.x, t = threadIdx.x;
  const int w = t >> 6, l = t & 63;

  __shared__ float sW[128 * 64];    // 32 KB producer staging
  __shared__ float sLv[7 * 128];
  __shared__ float scal[8];
  __shared__ float pub[8][5];

  // ================= Phase A: every block prefetches its batch inputs =================
  const float4* A4 = (const float4*)(nodef + (size_t)b * (NN * 3));
  const float4 a0 = A4[3*t], a1 = A4[3*t+1], a2 = A4[3*t+2];
  const int cid = curr_id[b], nid = next_id[b];
  const float4 st4 = *(const float4*)(state + b * 4);
  const float* xcp = nodef + ((size_t)b * NN + cid) * 3;
  const float* xnp = nodef + ((size_t)b * NN + nid) * 3;
  const float xc0 = xcp[0], xc1 = xcp[1], xc2 = xcp[2];
  const float xn0 = xnp[0], xn1 = xnp[1], xn2 = xnp[2];
  const float nf00 = nodef[(size_t)b * NN * 3];
  const float nf01 = nodef[(size_t)b * NN * 3 + 1];

  // ---- mask width detect: per-wave ballot over first 8 KB (mask buffer >= 512 KB)
  int mflag;
  {
    const longlong2 mv = ((const longlong2*)maskp)[t];
    const unsigned int w0 = (unsigned int)mv.x, w1 = (unsigned int)((unsigned long long)mv.x >> 32);
    const unsigned int w2 = (unsigned int)mv.y, w3 = (unsigned int)((unsigned long long)mv.y >> 32);
    int f = 0;
    if ((w0 | w1 | w2 | w3) & 0xFFFFFF00u) f |= 1;   // nonzero sub-word byte -> byte mask
    if ((w1 & 0xFFu) | (w3 & 0xFFu))       f |= 2;   // odd 32-bit word LSB -> int32 mask
    const unsigned long long B1 = __ballot(f & 1);
    const unsigned long long B2 = __ballot(f & 2);
    mflag = B1 ? 1 : (B2 ? 2 : 4);
  }

  // ---- mask for this thread's 4 nodes + depot-mask broadcast value (t<128)
  int mk0, mk1, mk2, mk3, mkd = 0;
  {
    const size_t off = (size_t)b * NN + 4 * (size_t)t;
    if (mflag == 1) {
      const unsigned int mm = *(const unsigned int*)((const unsigned char*)maskp + off);
      mk0 = mm & 0xFF; mk1 = (mm >> 8) & 0xFF; mk2 = (mm >> 16) & 0xFF; mk3 = (mm >> 24) & 0xFF;
      if (t < NE) mkd = ((const unsigned char*)maskp)[(size_t)b * NN];
    } else if (mflag == 2) {
      const int4 mm = *(const int4*)((const int*)maskp + off);
      mk0 = mm.x; mk1 = mm.y; mk2 = mm.z; mk3 = mm.w;
      if (t < NE) mkd = ((const int*)maskp)[(size_t)b * NN];
    } else {
      const longlong2* mp = (const longlong2*)maskp;
      const longlong2 u = mp[off / 2], v = mp[off / 2 + 1];
      mk0 = u.x != 0; mk1 = u.y != 0; mk2 = v.x != 0; mk3 = v.y != 0;
      if (t < NE) mkd = ((const long long*)maskp)[(size_t)b * NN] != 0;
    }
  }

  // ================= Phase A1: blocks 0-13 produce the weight table =================
  if (b < 14) {
    const int mi = b >> 1, hf = b & 1;      // matrix index, column-half
    const float* mat; int rowbase, nrows;
    switch (mi) {
      case 0: mat = wq;          rowbase = 0;  nrows = 7; break;
      case 1: mat = wq + 16384;  rowbase = 7;  nrows = 7; break;
      case 2: mat = wq + 32768;  rowbase = 14; nrows = 5; break;
      case 3: mat = wk;          rowbase = 19; nrows = 7; break;
      case 4: mat = wk + 16384;  rowbase = 26; nrows = 7; break;
      case 5: mat = wv;          rowbase = 33; nrows = 7; break;
      default: mat = wv + 16384; rowbase = 40; nrows = 7; break;
    }
    // stage column-half [128 j][64 e] (32 KB), coalesced float4
    #pragma unroll
    for (int i = 0; i < 4; ++i) {
      const int idx = i * 512 + t;            // 2048 float4 total
      const int j = idx >> 4, c4 = idx & 15;
      const float4 v = *(const float4*)(mat + j * 128 + hf * 64 + c4 * 4);
      *(float4*)(sW + j * 64 + c4 * 4) = v;
    }
    // left vectors (full 128-j range)
    for (int i = t; i < 896; i += 512) {
      const int r = i >> 7, j = i & 127;
      float lv;
      if (mi == 2) lv = (r < 4) ? Ws[r * 128 + j] : ((r == 4) ? bs[j] : 0.f);
      else lv = (r < 3) ? Wn[r * 128 + j] :
                (r == 3) ? bn[j] :
                (r < 6)  ? Wd[(r - 4) * 128 + j] : bd[j];
      sLv[r * 128 + j] = lv;
    }
    __syncthreads();
    if (t < nrows * 64) {
      const int r = t >> 6, el = t & 63;
      float acc = 0.f;
      #pragma unroll 16
      for (int j = 0; j < 128; ++j) acc += sLv[r * 128 + j] * sW[j * 64 + el];
      T[(rowbase + r) * NE + hf * 64 + el] = acc;
    }
    __threadfence();    // device-scope release of T before grid barrier
  }

  cg::this_grid().sync();

  // ================= Phase B =================
  // ---- epilogue columns (t<128): load early, consume at the end
  float evc = 0.f, eav0 = 0.f, eav1 = 0.f, eav2 = 0.f, ecv = 0.f, edv0 = 0.f, edv1 = 0.f, edv = 0.f;
  if (t < NE) {
    const int e = t;
    const float vn0 = T[33*NE+e], vn1 = T[34*NE+e], vn2 = T[35*NE+e], vn3 = T[36*NE+e];
    const float vd0 = T[37*NE+e], vd1 = T[38*NE+e], vd2 = T[39*NE+e];
    evc = (cid == 0) ? (xc0*vd0 + xc1*vd1 + vd2)
                     : (xc0*vn0 + xc1*vn1 + xc2*vn2 + vn3);
    eav0 = T[40*NE+e]; eav1 = T[41*NE+e]; eav2 = T[42*NE+e]; ecv = T[43*NE+e];
    edv0 = T[44*NE+e]; edv1 = T[45*NE+e]; edv  = T[46*NE+e];
  }

  // ---- every wave materializes q for e=l and e=l+64
  float qh[2];
  #pragma unroll
  for (int h = 0; h < 2; ++h) {
    const int e = l + 64 * h;
    const float cn0 = T[0*NE+e], cn1 = T[1*NE+e], cn2 = T[2*NE+e], cn3 = T[3*NE+e];
    const float cd0 = T[4*NE+e], cd1 = T[5*NE+e], cd2 = T[6*NE+e];
    const float nn0 = T[7*NE+e], nn1 = T[8*NE+e], nn2 = T[9*NE+e], nn3 = T[10*NE+e];
    const float nd0 = T[11*NE+e], nd1 = T[12*NE+e], nd2 = T[13*NE+e];
    const float s0 = T[14*NE+e], s1 = T[15*NE+e], s2 = T[16*NE+e], s3 = T[17*NE+e], s4 = T[18*NE+e];
    float q = (cid == 0) ? (xc0*cd0 + xc1*cd1 + cd2)
                         : (xc0*cn0 + xc1*cn1 + xc2*cn2 + cn3);
    q += (nid == 0) ? (xn0*nd0 + xn1*nd1 + nd2)
                    : (xn0*nn0 + xn1*nn1 + xn2*nn2 + nn3);
    q += st4.x*s0 + st4.y*s1 + st4.z*s2 + st4.w*s3 + s4;
    qh[h] = q;
  }

  // ---- wave w computes scalar w: {q.kc, q.ck, q.dk, Ak@q x3, Dk@q x2}
  {
    float tgl = 0.f, tgh = 0.f;
    if (w == 0) {
      #pragma unroll
      for (int h = 0; h < 2; ++h) {
        const int e = l + 64 * h;
        const float kn0 = T[19*NE+e], kn1 = T[20*NE+e], kn2 = T[21*NE+e], kn3 = T[22*NE+e];
        const float kd0 = T[23*NE+e], kd1 = T[24*NE+e], kd2 = T[25*NE+e];
        const float kc = (cid == 0) ? (xc0*kd0 + xc1*kd1 + kd2)
                                    : (xc0*kn0 + xc1*kn1 + xc2*kn2 + kn3);
        if (h == 0) tgl = kc; else tgh = kc;
      }
    } else {
      const int row = (w == 1) ? 29 : (w == 2) ? 32 : (w <= 5) ? (23 + w) : (24 + w);
      tgl = T[row*NE + l]; tgh = T[row*NE + 64 + l];
    }
    float p = qh[0] * tgl + qh[1] * tgh;
    #pragma unroll
    for (int o = 32; o; o >>= 1) p += __shfl_down(p, o, 64);
    if (l == 0) scal[w] = p;
  }
  __syncthreads();   // sync A: scal published

  const float qkc = scal[0], qck = scal[1], qdk = scal[2];
  const float gk0 = scal[3], gk1 = scal[4], gk2 = scal[5];
  const float gdk0 = scal[6], gdk1 = scal[7];

  // ---- compat for 4 register-resident nodes
  const float f0 = a0.x, f1 = a0.y, f2 = a0.z, f3 = a0.w;
  const float f4 = a1.x, f5 = a1.y, f6 = a1.z, f7 = a1.w;
  const float f8 = a2.x, f9 = a2.y, f10 = a2.z, f11 = a2.w;
  float c0, c1, c2, c3;
  if (t == 0) c0 = qkc + qdk + f0*gdk0 + f1*gdk1;           // node 0 = depot
  else        c0 = qkc + qck + f0*gk0 + f1*gk1 + f2*gk2;
  c1 = qkc + qck + f3*gk0 + f4*gk1 + f5*gk2;
  c2 = qkc + qck + f6*gk0 + f7*gk1 + f8*gk2;
  c3 = qkc + qck + f9*gk0 + f10*gk1 + f11*gk2;
  c0 = mk0 ? c0 * NORMC : -INFINITY;
  c1 = mk1 ? c1 * NORMC : -INFINITY;
  c2 = mk2 ? c2 * NORMC : -INFINITY;
  c3 = mk3 ? c3 * NORMC : -INFINITY;

  // ---- fused online-softmax reduction: per-thread -> wave -> block (ONE barrier)
  float mt = fmaxf(fmaxf(c0, c1), fmaxf(c2, c3));
  float e0 = (c0 > -INFINITY) ? __expf(c0 - mt) : 0.f;
  float e1 = (c1 > -INFINITY) ? __expf(c1 - mt) : 0.f;
  float e2 = (c2 > -INFINITY) ? __expf(c2 - mt) : 0.f;
  float e3 = (c3 > -INFINITY) ? __expf(c3 - mt) : 0.f;
  float lt = e0 + e1 + e2 + e3;
  float s0, s1, s2;
  if (t == 0) { s0 = 0.f; s1 = 0.f; s2 = 0.f; }             // exclude depot from S
  else        { s0 = e0*f0; s1 = e0*f1; s2 = e0*f2; }
  s0 += e1*f3 + e2*f6 + e3*f9;
  s1 += e1*f4 + e2*f7 + e3*f10;
  s2 += e1*f5 + e2*f8 + e3*f11;
  #pragma unroll
  for (int o = 32; o; o >>= 1) {
    const float mo = __shfl_down(mt, o, 64);
    const float lo = __shfl_down(lt, o, 64);
    const float t0 = __shfl_down(s0, o, 64);
    const float t1 = __shfl_down(s1, o, 64);
    const float t2 = __shfl_down(s2, o, 64);
    const float mm = fmaxf(mt, mo);
    const float wa = (mt > -INFINITY) ? __expf(mt - mm) : 0.f;
    const float wb = (mo > -INFINITY) ? __expf(mo - mm) : 0.f;
    lt = lt * wa + lo * wb;
    s0 = s0 * wa + t0 * wb;
    s1 = s1 * wa + t1 * wb;
    s2 = s2 * wa + t2 * wb;
    mt = mm;
  }
  if (l == 0) { pub[w][0] = mt; pub[w][1] = lt; pub[w][2] = s0; pub[w][3] = s1; pub[w][4] = s2; }
  __syncthreads();   // sync D: per-wave partials published

  // ---- epilogue on t<128 (combine 8 wave-partials; recompute depot term locally)
  if (t < NE) {
    float M = pub[0][0], L = pub[0][1], S0 = pub[0][2], S1 = pub[0][3], S2 = pub[0][4];
    #pragma unroll
    for (int i = 1; i < 8; ++i) {
      const float mo = pub[i][0];
      const float mm = fmaxf(M, mo);
      const float wa = (M  > -INFINITY) ? __expf(M  - mm) : 0.f;
      const float wb = (mo > -INFINITY) ? __expf(mo - mm) : 0.f;
      L  = L  * wa + pub[i][1] * wb;
      S0 = S0 * wa + pub[i][2] * wb;
      S1 = S1 * wa + pub[i][3] * wb;
      S2 = S2 * wa + pub[i][4] * wb;
      M = mm;
    }
    const float cd = mkd ? (qkc + qdk + nf00*gdk0 + nf01*gdk1) * NORMC : -INFINITY;
    const float ed = (cd > -INFINITY) ? __expf(cd - M) : 0.f;
    const float a0w = ed / L;
    const float hv = evc
      + (1.0f - a0w) * ecv
      + (S0*eav0 + S1*eav1 + S2*eav2) / L
      + a0w * (nf00*edv0 + nf01*edv1 + edv);
    out[(size_t)b * NE + t] = hv;
  }
}

extern "C" void kernel_launch(void* const* d_in, const int* in_sizes, int n_in,
                              void* d_out, int out_size, void* d_ws, size_t ws_size,
                              hipStream_t stream) {
  (void)in_sizes; (void)n_in; (void)out_size; (void)ws_size;
  const float* nodef   = (const float*)d_in[0];
  const float* state   = (const float*)d_in[1];
  const float* W_node  = (const float*)d_in[2];
  const float* b_node  = (const float*)d_in[3];
  const float* W_depot = (const float*)d_in[4];
  const float* b_depot = (const float*)d_in[5];
  const float* W_state = (const float*)d_in[6];
  const float* b_state = (const float*)d_in[7];
  const float* w_q     = (const float*)d_in[8];
  const float* w_k     = (const float*)d_in[9];
  const float* w_v     = (const float*)d_in[10];
  const int*   curr_id = (const int*)d_in[11];
  const int*   next_id = (const int*)d_in[12];
  const void*  maskp   = d_in[13];
  float* T   = (float*)d_ws;
  float* out = (float*)d_out;

  void* args[] = {
    (void*)&nodef, (void*)&state,
    (void*)&W_node, (void*)&b_node, (void*)&W_depot, (void*)&b_depot,
    (void*)&W_state, (void*)&b_state,
    (void*)&w_q, (void*)&w_k, (void*)&w_v,
    (void*)&curr_id, (void*)&next_id, (void*)&maskp,
    (void*)&T, (void*)&out
  };
  hipLaunchCooperativeKernel((const void*)fused_kernel, dim3(NB), dim3(512),
                             args, 0, stream);
}

// Round 7
// 15.574 us; speedup vs baseline: 3.1143x; 3.1143x over previous
//
#include <hip/hip_runtime.h>
#include <math.h>

#define NB 256
#define NN 2048
#define NE 128
#define NORMC 0.08838834764831845f   // 1/sqrt(128)
#define MAGIC 0x5F3759DF

// d_ws layout: int flags[14] (at offset 0), then T = 47 rows x 128 floats at +64 floats.
// T rows: 0-2 Qc_n 3 bQ1_n 4-5 Qc_d 6 bQ1_d   (wq1)
//         7-9 Qn_n 10 bQ2_n 11-12 Qn_d 13 bQ2_d (wq2)
//         14-17 Qs 18 bQ3                      (wq3)
//         19-21 Kc_n 22 bKc_n 23-24 Kc_d 25 bKc_d (wk1)
//         26-28 Ak 29 ck 30-31 Dk 32 dk        (wk2)
//         33-35 Vc_n 36 bVc_n 37-38 Vc_d 39 bVc_d (wv1)
//         40-42 Av 43 cv 44-45 Dv 46 dv        (wv2)

__global__ __launch_bounds__(512)
void fused_kernel(const float* __restrict__ nodef, const float* __restrict__ state,
                  const float* __restrict__ Wn, const float* __restrict__ bn,
                  const float* __restrict__ Wd, const float* __restrict__ bd,
                  const float* __restrict__ Ws, const float* __restrict__ bs,
                  const float* __restrict__ wq, const float* __restrict__ wk,
                  const float* __restrict__ wv,
                  const int* __restrict__ curr_id, const int* __restrict__ next_id,
                  const void* __restrict__ maskp,
                  int* __restrict__ flags, float* __restrict__ T,
                  float* __restrict__ out)
{
  const int b = blockIdx.x, t = threadIdx.x;
  const int w = t >> 6, l = t & 63;

  __shared__ float sW[128 * 64];    // 32 KB producer staging
  __shared__ float sLv[7 * 128];
  __shared__ float scal[8];
  __shared__ float pub[8][5];

  // ================= Phase A: every block prefetches its batch inputs =================
  const float4* A4 = (const float4*)(nodef + (size_t)b * (NN * 3));
  const float4 a0 = A4[3*t], a1 = A4[3*t+1], a2 = A4[3*t+2];
  const int cid = curr_id[b], nid = next_id[b];
  const float4 st4 = *(const float4*)(state + b * 4);
  const float* xcp = nodef + ((size_t)b * NN + cid) * 3;
  const float* xnp = nodef + ((size_t)b * NN + nid) * 3;
  const float xc0 = xcp[0], xc1 = xcp[1], xc2 = xcp[2];
  const float xn0 = xnp[0], xn1 = xnp[1], xn2 = xnp[2];
  const float nf00 = nodef[(size_t)b * NN * 3];
  const float nf01 = nodef[(size_t)b * NN * 3 + 1];

  // ---- mask width detect: per-wave ballot over first 8 KB (mask buffer >= 512 KB)
  int mflag;
  {
    const longlong2 mv = ((const longlong2*)maskp)[t];
    const unsigned int w0 = (unsigned int)mv.x, w1 = (unsigned int)((unsigned long long)mv.x >> 32);
    const unsigned int w2 = (unsigned int)mv.y, w3 = (unsigned int)((unsigned long long)mv.y >> 32);
    int f = 0;
    if ((w0 | w1 | w2 | w3) & 0xFFFFFF00u) f |= 1;   // nonzero sub-word byte -> byte mask
    if ((w1 & 0xFFu) | (w3 & 0xFFu))       f |= 2;   // odd 32-bit word LSB -> int32 mask
    const unsigned long long B1 = __ballot(f & 1);
    const unsigned long long B2 = __ballot(f & 2);
    mflag = B1 ? 1 : (B2 ? 2 : 4);
  }

  // ---- mask for this thread's 4 nodes + depot-mask value (t<128)
  int mk0, mk1, mk2, mk3, mkd = 0;
  {
    const size_t off = (size_t)b * NN + 4 * (size_t)t;
    if (mflag == 1) {
      const unsigned int mm = *(const unsigned int*)((const unsigned char*)maskp + off);
      mk0 = mm & 0xFF; mk1 = (mm >> 8) & 0xFF; mk2 = (mm >> 16) & 0xFF; mk3 = (mm >> 24) & 0xFF;
      if (t < NE) mkd = ((const unsigned char*)maskp)[(size_t)b * NN];
    } else if (mflag == 2) {
      const int4 mm = *(const int4*)((const int*)maskp + off);
      mk0 = mm.x; mk1 = mm.y; mk2 = mm.z; mk3 = mm.w;
      if (t < NE) mkd = ((const int*)maskp)[(size_t)b * NN];
    } else {
      const longlong2* mp = (const longlong2*)maskp;
      const longlong2 u = mp[off / 2], v = mp[off / 2 + 1];
      mk0 = u.x != 0; mk1 = u.y != 0; mk2 = v.x != 0; mk3 = v.y != 0;
      if (t < NE) mkd = ((const long long*)maskp)[(size_t)b * NN] != 0;
    }
  }

  // ================= Phase A1: blocks 0-13 produce the weight table =================
  if (b < 14) {
    const int mi = b >> 1, hf = b & 1;      // matrix index, column-half
    const float* mat; int rowbase, nrows;
    switch (mi) {
      case 0: mat = wq;          rowbase = 0;  nrows = 7; break;
      case 1: mat = wq + 16384;  rowbase = 7;  nrows = 7; break;
      case 2: mat = wq + 32768;  rowbase = 14; nrows = 5; break;
      case 3: mat = wk;          rowbase = 19; nrows = 7; break;
      case 4: mat = wk + 16384;  rowbase = 26; nrows = 7; break;
      case 5: mat = wv;          rowbase = 33; nrows = 7; break;
      default: mat = wv + 16384; rowbase = 40; nrows = 7; break;
    }
    // stage column-half [128 j][64 e] (32 KB)
    #pragma unroll
    for (int i = 0; i < 4; ++i) {
      const int idx = i * 512 + t;            // 2048 float4 total
      const int j = idx >> 4, c4 = idx & 15;
      const float4 v = *(const float4*)(mat + j * 128 + hf * 64 + c4 * 4);
      *(float4*)(sW + j * 64 + c4 * 4) = v;
    }
    // left vectors (full 128-j range)
    for (int i = t; i < 896; i += 512) {
      const int r = i >> 7, j = i & 127;
      float lv;
      if (mi == 2) lv = (r < 4) ? Ws[r * 128 + j] : ((r == 4) ? bs[j] : 0.f);
      else lv = (r < 3) ? Wn[r * 128 + j] :
                (r == 3) ? bn[j] :
                (r < 6)  ? Wd[(r - 4) * 128 + j] : bd[j];
      sLv[r * 128 + j] = lv;
    }
    __syncthreads();
    if (t < nrows * 64) {
      const int r = t >> 6, el = t & 63;
      float acc = 0.f;
      #pragma unroll 16
      for (int j = 0; j < 128; ++j) acc += sLv[r * 128 + j] * sW[j * 64 + el];
      T[(rowbase + r) * NE + hf * 64 + el] = acc;
    }
    __syncthreads();            // all T writes of this block issued & complete
    if (t == 0) {
      __threadfence();          // device-scope publish of T
      __hip_atomic_store(&flags[b], (int)MAGIC, __ATOMIC_RELEASE, __HIP_MEMORY_SCOPE_AGENT);
    }
  }

  // ================= wait for all 14 table halves =================
  if (t < 14) {
    while (__hip_atomic_load(&flags[t], __ATOMIC_ACQUIRE, __HIP_MEMORY_SCOPE_AGENT) != (int)MAGIC)
      __builtin_amdgcn_s_sleep(2);
  }
  __syncthreads();

  // ================= Phase B =================
  // ---- epilogue columns (t<128): load early, consume at the end
  float evc = 0.f, eav0 = 0.f, eav1 = 0.f, eav2 = 0.f, ecv = 0.f, edv0 = 0.f, edv1 = 0.f, edv = 0.f;
  if (t < NE) {
    const int e = t;
    const float vn0 = T[33*NE+e], vn1 = T[34*NE+e], vn2 = T[35*NE+e], vn3 = T[36*NE+e];
    const float vd0 = T[37*NE+e], vd1 = T[38*NE+e], vd2 = T[39*NE+e];
    evc = (cid == 0) ? (xc0*vd0 + xc1*vd1 + vd2)
                     : (xc0*vn0 + xc1*vn1 + xc2*vn2 + vn3);
    eav0 = T[40*NE+e]; eav1 = T[41*NE+e]; eav2 = T[42*NE+e]; ecv = T[43*NE+e];
    edv0 = T[44*NE+e]; edv1 = T[45*NE+e]; edv  = T[46*NE+e];
  }

  // ---- every wave materializes q for e=l and e=l+64
  float qh[2];
  #pragma unroll
  for (int h = 0; h < 2; ++h) {
    const int e = l + 64 * h;
    const float cn0 = T[0*NE+e], cn1 = T[1*NE+e], cn2 = T[2*NE+e], cn3 = T[3*NE+e];
    const float cd0 = T[4*NE+e], cd1 = T[5*NE+e], cd2 = T[6*NE+e];
    const float nn0 = T[7*NE+e], nn1 = T[8*NE+e], nn2 = T[9*NE+e], nn3 = T[10*NE+e];
    const float nd0 = T[11*NE+e], nd1 = T[12*NE+e], nd2 = T[13*NE+e];
    const float s0 = T[14*NE+e], s1 = T[15*NE+e], s2 = T[16*NE+e], s3 = T[17*NE+e], s4 = T[18*NE+e];
    float q = (cid == 0) ? (xc0*cd0 + xc1*cd1 + cd2)
                         : (xc0*cn0 + xc1*cn1 + xc2*cn2 + cn3);
    q += (nid == 0) ? (xn0*nd0 + xn1*nd1 + nd2)
                    : (xn0*nn0 + xn1*nn1 + xn2*nn2 + nn3);
    q += st4.x*s0 + st4.y*s1 + st4.z*s2 + st4.w*s3 + s4;
    qh[h] = q;
  }

  // ---- wave w computes scalar w: {q.kc, q.ck, q.dk, Ak@q x3, Dk@q x2}
  {
    float tgl = 0.f, tgh = 0.f;
    if (w == 0) {
      #pragma unroll
      for (int h = 0; h < 2; ++h) {
        const int e = l + 64 * h;
        const float kn0 = T[19*NE+e], kn1 = T[20*NE+e], kn2 = T[21*NE+e], kn3 = T[22*NE+e];
        const float kd0 = T[23*NE+e], kd1 = T[24*NE+e], kd2 = T[25*NE+e];
        const float kc = (cid == 0) ? (xc0*kd0 + xc1*kd1 + kd2)
                                    : (xc0*kn0 + xc1*kn1 + xc2*kn2 + kn3);
        if (h == 0) tgl = kc; else tgh = kc;
      }
    } else {
      const int row = (w == 1) ? 29 : (w == 2) ? 32 : (w <= 5) ? (23 + w) : (24 + w);
      tgl = T[row*NE + l]; tgh = T[row*NE + 64 + l];
    }
    float p = qh[0] * tgl + qh[1] * tgh;
    #pragma unroll
    for (int o = 32; o; o >>= 1) p += __shfl_down(p, o, 64);
    if (l == 0) scal[w] = p;
  }
  __syncthreads();   // sync A: scal published

  const float qkc = scal[0], qck = scal[1], qdk = scal[2];
  const float gk0 = scal[3], gk1 = scal[4], gk2 = scal[5];
  const float gdk0 = scal[6], gdk1 = scal[7];

  // ---- compat for 4 register-resident nodes
  const float f0 = a0.x, f1 = a0.y, f2 = a0.z, f3 = a0.w;
  const float f4 = a1.x, f5 = a1.y, f6 = a1.z, f7 = a1.w;
  const float f8 = a2.x, f9 = a2.y, f10 = a2.z, f11 = a2.w;
  float c0, c1, c2, c3;
  if (t == 0) c0 = qkc + qdk + f0*gdk0 + f1*gdk1;           // node 0 = depot
  else        c0 = qkc + qck + f0*gk0 + f1*gk1 + f2*gk2;
  c1 = qkc + qck + f3*gk0 + f4*gk1 + f5*gk2;
  c2 = qkc + qck + f6*gk0 + f7*gk1 + f8*gk2;
  c3 = qkc + qck + f9*gk0 + f10*gk1 + f11*gk2;
  c0 = mk0 ? c0 * NORMC : -INFINITY;
  c1 = mk1 ? c1 * NORMC : -INFINITY;
  c2 = mk2 ? c2 * NORMC : -INFINITY;
  c3 = mk3 ? c3 * NORMC : -INFINITY;

  // ---- fused online-softmax reduction: per-thread -> wave -> block (ONE barrier)
  float mt = fmaxf(fmaxf(c0, c1), fmaxf(c2, c3));
  float e0 = (c0 > -INFINITY) ? __expf(c0 - mt) : 0.f;
  float e1 = (c1 > -INFINITY) ? __expf(c1 - mt) : 0.f;
  float e2 = (c2 > -INFINITY) ? __expf(c2 - mt) : 0.f;
  float e3 = (c3 > -INFINITY) ? __expf(c3 - mt) : 0.f;
  float lt = e0 + e1 + e2 + e3;
  float s0, s1, s2;
  if (t == 0) { s0 = 0.f; s1 = 0.f; s2 = 0.f; }             // exclude depot from S
  else        { s0 = e0*f0; s1 = e0*f1; s2 = e0*f2; }
  s0 += e1*f3 + e2*f6 + e3*f9;
  s1 += e1*f4 + e2*f7 + e3*f10;
  s2 += e1*f5 + e2*f8 + e3*f11;
  #pragma unroll
  for (int o = 32; o; o >>= 1) {
    const float mo = __shfl_down(mt, o, 64);
    const float lo = __shfl_down(lt, o, 64);
    const float t0 = __shfl_down(s0, o, 64);
    const float t1 = __shfl_down(s1, o, 64);
    const float t2 = __shfl_down(s2, o, 64);
    const float mm = fmaxf(mt, mo);
    const float wa = (mt > -INFINITY) ? __expf(mt - mm) : 0.f;
    const float wb = (mo > -INFINITY) ? __expf(mo - mm) : 0.f;
    lt = lt * wa + lo * wb;
    s0 = s0 * wa + t0 * wb;
    s1 = s1 * wa + t1 * wb;
    s2 = s2 * wa + t2 * wb;
    mt = mm;
  }
  if (l == 0) { pub[w][0] = mt; pub[w][1] = lt; pub[w][2] = s0; pub[w][3] = s1; pub[w][4] = s2; }
  __syncthreads();   // sync D: per-wave partials published

  // ---- epilogue on t<128 (combine 8 wave-partials; recompute depot term locally)
  if (t < NE) {
    float M = pub[0][0], L = pub[0][1], S0 = pub[0][2], S1 = pub[0][3], S2 = pub[0][4];
    #pragma unroll
    for (int i = 1; i < 8; ++i) {
      const float mo = pub[i][0];
      const float mm = fmaxf(M, mo);
      const float wa = (M  > -INFINITY) ? __expf(M  - mm) : 0.f;
      const float wb = (mo > -INFINITY) ? __expf(mo - mm) : 0.f;
      L  = L  * wa + pub[i][1] * wb;
      S0 = S0 * wa + pub[i][2] * wb;
      S1 = S1 * wa + pub[i][3] * wb;
      S2 = S2 * wa + pub[i][4] * wb;
      M = mm;
    }
    const float cd = mkd ? (qkc + qdk + nf00*gdk0 + nf01*gdk1) * NORMC : -INFINITY;
    const float ed = (cd > -INFINITY) ? __expf(cd - M) : 0.f;
    const float a0w = ed / L;
    const float hv = evc
      + (1.0f - a0w) * ecv
      + (S0*eav0 + S1*eav1 + S2*eav2) / L
      + a0w * (nf00*edv0 + nf01*edv1 + edv);
    out[(size_t)b * NE + t] = hv;
  }
}

extern "C" void kernel_launch(void* const* d_in, const int* in_sizes, int n_in,
                              void* d_out, int out_size, void* d_ws, size_t ws_size,
                              hipStream_t stream) {
  (void)in_sizes; (void)n_in; (void)out_size; (void)ws_size;
  const float* nodef   = (const float*)d_in[0];
  const float* state   = (const float*)d_in[1];
  const float* W_node  = (const float*)d_in[2];
  const float* b_node  = (const float*)d_in[3];
  const float* W_depot = (const float*)d_in[4];
  const float* b_depot = (const float*)d_in[5];
  const float* W_state = (const float*)d_in[6];
  const float* b_state = (const float*)d_in[7];
  const float* w_q     = (const float*)d_in[8];
  const float* w_k     = (const float*)d_in[9];
  const float* w_v     = (const float*)d_in[10];
  const int*   curr_id = (const int*)d_in[11];
  const int*   next_id = (const int*)d_in[12];
  const void*  maskp   = d_in[13];
  int*   flags = (int*)d_ws;
  float* T     = (float*)d_ws + 64;
  float* out   = (float*)d_out;

  hipLaunchKernelGGL(fused_kernel, dim3(NB), dim3(512), 0, stream,
                     nodef, state, W_node, b_node, W_depot, b_depot,
                     W_state, b_state, w_q, w_k, w_v,
                     curr_id, next_id, maskp, flags, T, out);
}

// Round 8
// 15.142 us; speedup vs baseline: 3.2033x; 1.0286x over previous
//
#include <hip/hip_runtime.h>
#include <math.h>

#define NB 256
#define NN 2048
#define NE 128
#define NORMC 0.08838834764831845f   // 1/sqrt(128)

// ---- table row layout in d_ws (47 rows x 128 floats, then mflag int) ----
// 0-2  Qc_n  (Wn@wq1)   3 bQ1_n (bn@wq1)   4-5 Qc_d (Wd@wq1)   6 bQ1_d (bd@wq1)
// 7-9  Qn_n  (Wn@wq2)  10 bQ2_n (bn@wq2)  11-12 Qn_d (Wd@wq2) 13 bQ2_d (bd@wq2)
// 14-17 Qs   (Ws@wq3)  18 bQ3  (bs@wq3)
// 19-21 Kc_n (Wn@wk1)  22 bKc_n (bn@wk1)  23-24 Kc_d (Wd@wk1) 25 bKc_d (bd@wk1)
// 26-28 Ak   (Wn@wk2)  29 ck   (bn@wk2)   30-31 Dk  (Wd@wk2)  32 dk   (bd@wk2)
// 33-35 Vc_n (Wn@wv1)  36 bVc_n (bn@wv1)  37-38 Vc_d (Wd@wv1) 39 bVc_d (bd@wv1)
// 40-42 Av   (Wn@wv2)  43 cv   (bn@wv2)   44-45 Dv  (Wd@wv2)  46 dv   (bd@wv2)

__device__ __constant__ int c_lid[47] = {
  0,1,2,3, 4,5,6,          // wq1
  0,1,2,3, 4,5,6,          // wq2
  7,8,9,10,11,             // wq3
  0,1,2,3, 4,5,6,          // wk1
  0,1,2,3, 4,5,6,          // wk2
  0,1,2,3, 4,5,6,          // wv1
  0,1,2,3, 4,5,6           // wv2
};
__device__ __constant__ int c_rid[47] = {
  0,0,0,0,0,0,0,
  1,1,1,1,1,1,1,
  2,2,2,2,2,
  3,3,3,3,3,3,3,
  4,4,4,4,4,4,4,
  5,5,5,5,5,5,5,
  6,6,6,6,6,6,6
};

__global__ __launch_bounds__(128)
void k1_tables(const float* __restrict__ Wn, const float* __restrict__ bn,
               const float* __restrict__ Wd, const float* __restrict__ bd,
               const float* __restrict__ Ws, const float* __restrict__ bs,
               const float* __restrict__ wq, const float* __restrict__ wk,
               const float* __restrict__ wv, const void* __restrict__ maskp,
               float* __restrict__ T)
{
  const int r = blockIdx.x, e = threadIdx.x;
  if (r == 47) {
    // mask element-width detect: bit0 -> 1-byte, bit1 -> 4-byte, none -> 8-byte
    __shared__ int sflag;
    if (e == 0) sflag = 0;
    __syncthreads();
    const unsigned char* mb = (const unsigned char*)maskp;
    int f = 0;
    #pragma unroll
    for (int i = 0; i < 32; ++i) {
      int idx = e * 32 + i;           // scans first 4096 bytes (buffer >= 512 KB)
      unsigned char v = mb[idx];
      if (v) { if (idx & 3) f |= 1; else if (idx & 7) f |= 2; }
    }
    if (f) atomicOr(&sflag, f);
    __syncthreads();
    if (e == 0) ((int*)T)[47 * NE] = sflag;
    return;
  }
  const int li = c_lid[r], ri = c_rid[r];
  const float* lv =
    (li < 3)  ? Wn + li * NE :
    (li == 3) ? bn :
    (li < 6)  ? Wd + (li - 4) * NE :
    (li == 6) ? bd :
    (li < 11) ? Ws + (li - 7) * NE : bs;
  const float* rv =
    (ri == 0) ? wq :
    (ri == 1) ? wq + 128 * NE :
    (ri == 2) ? wq + 256 * NE :
    (ri == 3) ? wk :
    (ri == 4) ? wk + 128 * NE :
    (ri == 5) ? wv : wv + 128 * NE;
  float acc = 0.f;
  #pragma unroll 32
  for (int j = 0; j < 128; ++j) acc += lv[j] * rv[j * NE + e];
  T[r * NE + e] = acc;
}

__global__ __launch_bounds__(1024)
void k2_main(const float* __restrict__ nodef,   // [B,N,3]
             const float* __restrict__ state,   // [B,4]
             const int*   __restrict__ curr_id,
             const int*   __restrict__ next_id,
             const void*  __restrict__ maskp,
             const float* __restrict__ T,       // tables from k1
             float* __restrict__ out)           // [B,128]
{
  const int b = blockIdx.x, t = threadIdx.x;

  __shared__ float qv[NE], kcs[NE];
  __shared__ float scal[8];
  __shared__ float redm[16], redsum[64];
  __shared__ float sse0;

  // ---- uniform scalars (issue early; scalar-unit loads)
  const int mflag = ((const int*)T)[47 * NE];
  const int cid = curr_id[b], nid = next_id[b];
  const float* xcp = nodef + ((size_t)b * NN + cid) * 3;
  const float* xnp = nodef + ((size_t)b * NN + nid) * 3;
  const float xc0 = xcp[0], xc1 = xcp[1], xc2 = xcp[2];
  const float xn0 = xnp[0], xn1 = xnp[1], xn2 = xnp[2];
  const float st0 = state[b*4], st1 = state[b*4+1], st2 = state[b*4+2], st3 = state[b*4+3];
  const float nf00 = nodef[(size_t)b * NN * 3];       // depot coords
  const float nf01 = nodef[(size_t)b * NN * 3 + 1];

  // ---- per-thread node feats (2 nodes), register resident
  const float2* f2 = (const float2*)(nodef + (size_t)b * NN * 3);
  const float2 p0 = f2[3*t], p1 = f2[3*t+1], p2 = f2[3*t+2];
  // node n0=2t feats: p0.x p0.y p1.x ; node n1=2t+1 feats: p1.y p2.x p2.y

  // ---- mask for the 2 nodes
  long long mk0, mk1;
  {
    const size_t off = (size_t)b * NN + 2*t;
    if (mflag & 1)      { const unsigned char* m = (const unsigned char*)maskp; mk0 = m[off]; mk1 = m[off+1]; }
    else if (mflag & 2) { const int* m = (const int*)maskp;                     mk0 = m[off]; mk1 = m[off+1]; }
    else                { const long long* m = (const long long*)maskp;         mk0 = m[off]; mk1 = m[off+1]; }
  }

  // ---- prefetch scal-dot target rows (groups 1-7) before sync
  float tg0 = 0.f, tg1 = 0.f;
  {
    const int gg = t >> 6, l = t & 63;
    if (t < 512 && gg >= 1) {
      const float* vg = (gg == 1) ? T + 29*NE :
                        (gg == 2) ? T + 32*NE :
                        (gg <= 5) ? T + (23 + gg)*NE :   // 26,27,28
                                    T + (24 + gg)*NE;    // 30,31
      tg0 = vg[l]; tg1 = vg[64 + l];
    }
  }

  // ---- t<128: materialize q, kc from tables; prefetch vc + epilogue rows
  float vc_r = 0.f, eav0=0.f, eav1=0.f, eav2=0.f, ecv=0.f, edv0=0.f, edv1=0.f, edv=0.f;
  if (t < NE) {
    const int e = t;
    float q, kc;
    if (cid == 0) {
      q  = xc0*T[ 4*NE+e] + xc1*T[ 5*NE+e] + T[ 6*NE+e];
      kc = xc0*T[23*NE+e] + xc1*T[24*NE+e] + T[25*NE+e];
      vc_r = xc0*T[37*NE+e] + xc1*T[38*NE+e] + T[39*NE+e];
    } else {
      q  = xc0*T[ 0*NE+e] + xc1*T[ 1*NE+e] + xc2*T[ 2*NE+e] + T[ 3*NE+e];
      kc = xc0*T[19*NE+e] + xc1*T[20*NE+e] + xc2*T[21*NE+e] + T[22*NE+e];
      vc_r = xc0*T[33*NE+e] + xc1*T[34*NE+e] + xc2*T[35*NE+e] + T[36*NE+e];
    }
    if (nid == 0) q += xn0*T[11*NE+e] + xn1*T[12*NE+e] + T[13*NE+e];
    else          q += xn0*T[ 7*NE+e] + xn1*T[ 8*NE+e] + xn2*T[ 9*NE+e] + T[10*NE+e];
    q += st0*T[14*NE+e] + st1*T[15*NE+e] + st2*T[16*NE+e] + st3*T[17*NE+e] + T[18*NE+e];
    qv[e] = q; kcs[e] = kc;
    eav0 = T[40*NE+e]; eav1 = T[41*NE+e]; eav2 = T[42*NE+e]; ecv = T[43*NE+e];
    edv0 = T[44*NE+e]; edv1 = T[45*NE+e]; edv  = T[46*NE+e];
  }
  __syncthreads();

  // ---- 8 scalar dots: {q.kc, q.ck, q.dk, Ak@q (3), Dk@q (2)}
  if (t < 512) {
    const int gg = t >> 6, l = t & 63;
    if (gg == 0) { tg0 = kcs[l]; tg1 = kcs[64 + l]; }
    float p = qv[l] * tg0 + qv[64 + l] * tg1;
    #pragma unroll
    for (int o = 32; o; o >>= 1) p += __shfl_down(p, o, 64);
    if (l == 0) scal[gg] = p;
  }
  __syncthreads();

  const float qkc = scal[0], qck = scal[1], qdk = scal[2];
  const float gk0 = scal[3], gk1 = scal[4], gk2 = scal[5];
  const float gdk0 = scal[6], gdk1 = scal[7];

  // ---- compat for 2 register-resident nodes + block max
  float c0, c1;
  if (t == 0) c0 = qkc + qdk + p0.x*gdk0 + p0.y*gdk1;            // node 0 = depot
  else        c0 = qkc + qck + p0.x*gk0 + p0.y*gk1 + p1.x*gk2;
  c1 = qkc + qck + p1.y*gk0 + p2.x*gk1 + p2.y*gk2;
  c0 = mk0 ? c0 * NORMC : -INFINITY;
  c1 = mk1 ? c1 * NORMC : -INFINITY;

  float lmax = fmaxf(c0, c1);
  #pragma unroll
  for (int o = 32; o; o >>= 1) lmax = fmaxf(lmax, __shfl_down(lmax, o, 64));
  if ((t & 63) == 0) redm[t >> 6] = lmax;
  __syncthreads();
  float m = redm[0];
  #pragma unroll
  for (int i = 1; i < 16; ++i) m = fmaxf(m, redm[i]);

  // ---- exp + denom + 3-component weighted feature sums (n>=1)
  const float ex0 = __expf(c0 - m);
  const float ex1 = __expf(c1 - m);
  if (t == 0) sse0 = ex0;
  float le = ex0 + ex1;
  float s0, s1, s2;
  if (t == 0) { s0 = ex1*p1.y; s1 = ex1*p2.x; s2 = ex1*p2.y; }   // exclude depot node
  else {
    s0 = ex0*p0.x + ex1*p1.y;
    s1 = ex0*p0.y + ex1*p2.x;
    s2 = ex0*p1.x + ex1*p2.y;
  }
  #pragma unroll
  for (int o = 32; o; o >>= 1) {
    le += __shfl_down(le, o, 64);
    s0 += __shfl_down(s0, o, 64);
    s1 += __shfl_down(s1, o, 64);
    s2 += __shfl_down(s2, o, 64);
  }
  if ((t & 63) == 0) {
    const int w = t >> 6;
    redsum[w] = le; redsum[16+w] = s0; redsum[32+w] = s1; redsum[48+w] = s2;
  }
  __syncthreads();

  // ---- epilogue on t<128
  if (t < NE) {
    float L = 0, S0 = 0, S1 = 0, S2 = 0;
    #pragma unroll
    for (int i = 0; i < 16; ++i) {
      L += redsum[i]; S0 += redsum[16+i]; S1 += redsum[32+i]; S2 += redsum[48+i];
    }
    const float a0 = sse0 / L;
    const float hv = vc_r
      + (1.0f - a0) * ecv
      + (S0*eav0 + S1*eav1 + S2*eav2) / L
      + a0 * (nf00*edv0 + nf01*edv1 + edv);
    out[(size_t)b * NE + t] = hv;
  }
}

extern "C" void kernel_launch(void* const* d_in, const int* in_sizes, int n_in,
                              void* d_out, int out_size, void* d_ws, size_t ws_size,
                              hipStream_t stream) {
  (void)in_sizes; (void)n_in; (void)out_size; (void)ws_size;
  const float* nodef   = (const float*)d_in[0];
  const float* state   = (const float*)d_in[1];
  const float* W_node  = (const float*)d_in[2];
  const float* b_node  = (const float*)d_in[3];
  const float* W_depot = (const float*)d_in[4];
  const float* b_depot = (const float*)d_in[5];
  const float* W_state = (const float*)d_in[6];
  const float* b_state = (const float*)d_in[7];
  const float* w_q     = (const float*)d_in[8];
  const float* w_k     = (const float*)d_in[9];
  const float* w_v     = (const float*)d_in[10];
  const int*   curr_id = (const int*)d_in[11];
  const int*   next_id = (const int*)d_in[12];
  const void*  maskp   = d_in[13];
  float* T   = (float*)d_ws;
  float* out = (float*)d_out;

  hipLaunchKernelGGL(k1_tables, dim3(48), dim3(128), 0, stream,
                     W_node, b_node, W_depot, b_depot, W_state, b_state,
                     w_q, w_k, w_v, maskp, T);
  hipLaunchKernelGGL(k2_main, dim3(NB), dim3(1024), 0, stream,
                     nodef, state, curr_id, next_id, maskp, T, out);
}